// Round 8
// baseline (228.023 us; speedup 1.0000x reference)
//
#include <hip/hip_runtime.h>

typedef unsigned short u16;
typedef unsigned int u32;
typedef short bf16x8 __attribute__((ext_vector_type(8)));
typedef float f32x4 __attribute__((ext_vector_type(4)));

#define CSC 0.18033688011112042f   // (1/8) * log2(e)
#define MFMA16 __builtin_amdgcn_mfma_f32_16x16x32_bf16

// ---------- bf16 helpers ----------
__device__ __forceinline__ u16 f2bf(float f) {
    union { float f; unsigned u; } x; x.f = f;
    unsigned r = x.u + 0x7fffu + ((x.u >> 16) & 1u);
    return (u16)(r >> 16);
}
__device__ __forceinline__ float bf2f(u16 v) {
    union { unsigned u; float f; } x; x.u = ((unsigned)v) << 16;
    return x.f;
}
__device__ __forceinline__ float exp2_fast(float x) {
#if __has_builtin(__builtin_amdgcn_exp2f)
    return __builtin_amdgcn_exp2f(x);
#else
    return exp2f(x);
#endif
}
// pack two fp32 -> bf16x2 (round-half-up) via v_perm_b32
__device__ __forceinline__ u32 pack2bf(float a, float b) {
    union { float f; u32 u; } xa, xb; xa.f = a; xb.f = b;
#if __has_builtin(__builtin_amdgcn_perm)
    return __builtin_amdgcn_perm(xb.u + 0x8000u, xa.u + 0x8000u, 0x07060302u);
#else
    return ((xa.u + 0x8000u) >> 16) | ((xb.u + 0x8000u) & 0xffff0000u);
#endif
}
__device__ __forceinline__ void gl_lds16(const u16* g, u16* l) {
#if __has_builtin(__builtin_amdgcn_global_load_lds)
    __builtin_amdgcn_global_load_lds(
        (const __attribute__((address_space(1))) unsigned int*)g,
        (__attribute__((address_space(3))) unsigned int*)l, 16, 0, 0);
#else
    *(bf16x8*)l = *(const bf16x8*)g;
#endif
}
__device__ __forceinline__ int ileave(int x) {   // per-32 stored-key interleave
    return (x < 16) ? (x << 1) : (((x - 16) << 1) | 1);
}

// ---------- fp32 -> bf16, all inputs in one launch ----------
__global__ void cvt_all_kernel(const float* __restrict__ x, const float* __restrict__ wq,
                               const float* __restrict__ wk, const float* __restrict__ wv,
                               const float* __restrict__ wo,
                               u16* __restrict__ xb, u16* __restrict__ qkvw,
                               u16* __restrict__ ow) {
    int i = blockIdx.x * 256 + threadIdx.x;       // 0..2097151
    const float4* src;
    ushort4* dst;
    if (i < 1048576) {
        src = (const float4*)x + i;
        dst = (ushort4*)xb + i;
    } else {
        int r = i - 1048576;
        int m = r >> 18;
        int off = r & 262143;
        const float* s4 = (m == 0) ? wq : (m == 1) ? wk : (m == 2) ? wv : wo;
        u16* d = (m < 3) ? (qkvw + (size_t)m * 1048576) : ow;
        src = (const float4*)s4 + off;
        dst = (ushort4*)d + off;
    }
    float4 v = *src;
    ushort4 o;
    o.x = f2bf(v.x); o.y = f2bf(v.y); o.z = f2bf(v.z); o.w = f2bf(v.w);
    *dst = o;
}

// ---------- RoPE in-place, vectorized b128; q additionally pre-scaled by CSC ----------
__global__ void rope_kernel(u16* __restrict__ qb, u16* __restrict__ kb) {
    int idx = blockIdx.x * 256 + threadIdx.x;
    u16* buf;
    float scale;
    if (blockIdx.y == 0) { buf = qb; scale = CSC; } else { buf = kb; scale = 1.0f; }
    int g   = idx & 7;
    int row = idx >> 3;
    int s   = row & 2047;
    u16* p = buf + (size_t)row * 64 + g * 8;
    bf16x8 v = *(bf16x8*)p;
    bf16x8 o;
    #pragma unroll
    for (int q = 0; q < 4; ++q) {
        int i = g * 4 + q;
        float inv = exp2_fast((float)i * -0.4152410118609203f);  // 10000^(-i/32)
        float ang = (float)s * inv;
        float sn, cs;
        sincosf(ang, &sn, &cs);
        float e  = bf2f(((u16*)&v)[2 * q]);
        float od = bf2f(((u16*)&v)[2 * q + 1]);
        ((u16*)&o)[2 * q]     = f2bf((e * cs - od * sn) * scale);
        ((u16*)&o)[2 * q + 1] = f2bf((od * cs + e * sn) * scale);
    }
    *(bf16x8*)p = o;
}

// ---------- QKV GEMM: 128x128 tile, BK=32, C = A * Bw^T, N=3072 (R5-proven) ----------
__global__ __launch_bounds__(256) void gemm_qkv(const u16* __restrict__ A,
                                                const u16* __restrict__ Bw,
                                                u16* __restrict__ C, int K) {
    __shared__ __align__(16) u16 SH[8448];
    u16* As = SH;
    u16* Bs = SH + 4096;
    const int tid  = threadIdx.x;
    const int bm   = blockIdx.x * 128;
    const int bn   = blockIdx.y * 128;
    const int wave = tid >> 6, lane = tid & 63;
    const int wm   = (wave >> 1) * 64, wn = (wave & 1) * 64;
    const int l16  = lane & 15, quad = lane >> 4;
    const int mat  = bn >> 10;

    f32x4 acc[4][4];
    #pragma unroll
    for (int i = 0; i < 4; i++)
        #pragma unroll
        for (int j = 0; j < 4; j++)
            #pragma unroll
            for (int e = 0; e < 4; e++) acc[i][j][e] = 0.0f;

    const int srow = tid >> 2, scol = (tid & 3) * 8;
    const u16* gA0 = A  + (size_t)(bm + srow) * K + scol;
    const u16* gA1 = A  + (size_t)(bm + 64 + srow) * K + scol;
    const u16* gB0 = Bw + (size_t)(bn + srow) * K + scol;
    const u16* gB1 = Bw + (size_t)(bn + 64 + srow) * K + scol;
    u16* lA0 = &As[(size_t)tid * 8];
    u16* lA1 = &As[(size_t)(tid + 256) * 8];
    u16* lB0 = &Bs[(size_t)tid * 8];
    u16* lB1 = &Bs[(size_t)(tid + 256) * 8];

    for (int k0 = 0; k0 < K; k0 += 32) {
        __syncthreads();
        gl_lds16(gA0 + k0, lA0);
        gl_lds16(gA1 + k0, lA1);
        gl_lds16(gB0 + k0, lB0);
        gl_lds16(gB1 + k0, lB1);
        __syncthreads();
        bf16x8 af[4], bfr[4];
        #pragma unroll
        for (int i = 0; i < 4; i++) af[i]  = *(const bf16x8*)&As[(wm + i * 16 + l16) * 32 + quad * 8];
        #pragma unroll
        for (int j = 0; j < 4; j++) bfr[j] = *(const bf16x8*)&Bs[(wn + j * 16 + l16) * 32 + quad * 8];
        #pragma unroll
        for (int i = 0; i < 4; i++)
            #pragma unroll
            for (int j = 0; j < 4; j++)
                acc[i][j] = MFMA16(af[i], bfr[j], acc[i][j], 0, 0, 0);
    }

    const int b  = bm >> 11, sb = bm & 2047;
    if (mat < 2) {
        #pragma unroll
        for (int pass = 0; pass < 2; ++pass) {
            __syncthreads();
            if ((wn >> 6) == pass) {
                #pragma unroll
                for (int i = 0; i < 4; i++)
                    #pragma unroll
                    for (int j = 0; j < 4; j++)
                        #pragma unroll
                        for (int r = 0; r < 4; r++) {
                            int rl = wm + i * 16 + quad * 4 + r;
                            int cl = j * 16 + l16;
                            SH[rl * 66 + cl] = f2bf(acc[i][j][r]);
                        }
            }
            __syncthreads();
            int rl   = tid >> 1;
            int half = (tid & 1) * 32;
            int c    = (bn + pass * 64) & 1023;
            int h    = c >> 6;
            int s    = sb + rl;
            u16* dst = C + (size_t)mat * 4194304 +
                       (((size_t)(b * 16 + h) * 2048 + s) * 64) + half;
            const u16* srcp = &SH[rl * 66 + half];
            #pragma unroll
            for (int kk = 0; kk < 4; ++kk)
                *(bf16x8*)(dst + kk * 8) = *(const bf16x8*)(srcp + kk * 8);
        }
    } else {
        #pragma unroll
        for (int pass = 0; pass < 2; ++pass) {
            __syncthreads();
            if ((wn >> 6) == pass) {
                #pragma unroll
                for (int i = 0; i < 4; i++)
                    #pragma unroll
                    for (int j = 0; j < 4; j++)
                        #pragma unroll
                        for (int r = 0; r < 4; r++) {
                            int row = j * 16 + l16;
                            int ml  = wm + i * 16 + quad * 4 + r;
                            int sp  = (ml & ~31) | ileave(ml & 31);
                            SH[row * 130 + sp] = f2bf(acc[i][j][r]);
                        }
            }
            __syncthreads();
            int row = tid >> 2, seg = tid & 3;
            int cc  = (bn + pass * 64 + row) & 1023;
            int h = cc >> 6, dv = cc & 63;
            u16* dst = C + (size_t)8388608 +
                       (((size_t)(b * 16 + h) * 64 + dv) * 2048) + sb + seg * 32;
            const u16* srcp = &SH[row * 130 + seg * 32];
            #pragma unroll
            for (int kk = 0; kk < 4; ++kk)
                *(bf16x8*)(dst + kk * 8) = *(const bf16x8*)(srcp + kk * 8);
        }
    }
}

// ---------- O-proj GEMM: 128x64 tile, BK=32, fp32 out [M,1024] (R5-proven) ----------
__global__ __launch_bounds__(256, 2) void gemm_out(const u16* __restrict__ A,
                                                   const u16* __restrict__ Bw,
                                                   float* __restrict__ C, int K) {
    __shared__ __align__(16) u16 As[128 * 32];
    __shared__ __align__(16) u16 Bs[64 * 32];
    const int tid  = threadIdx.x;
    const int bm   = blockIdx.x * 128;
    const int bn   = blockIdx.y * 64;
    const int wave = tid >> 6, lane = tid & 63;
    const int wm   = wave * 32;
    const int l16  = lane & 15, quad = lane >> 4;

    f32x4 acc[2][4];
    #pragma unroll
    for (int i = 0; i < 2; i++)
        #pragma unroll
        for (int j = 0; j < 4; j++)
            #pragma unroll
            for (int e = 0; e < 4; e++) acc[i][j][e] = 0.0f;

    const int srow = tid >> 2, scol = (tid & 3) * 8;
    const u16* gA0 = A  + (size_t)(bm + srow) * K + scol;
    const u16* gA1 = A  + (size_t)(bm + 64 + srow) * K + scol;
    const u16* gB0 = Bw + (size_t)(bn + srow) * K + scol;
    u16* lA0 = &As[(size_t)tid * 8];
    u16* lA1 = &As[(size_t)(tid + 256) * 8];
    u16* lB0 = &Bs[(size_t)tid * 8];

    for (int k0 = 0; k0 < K; k0 += 32) {
        __syncthreads();
        gl_lds16(gA0 + k0, lA0);
        gl_lds16(gA1 + k0, lA1);
        gl_lds16(gB0 + k0, lB0);
        __syncthreads();
        bf16x8 af[2], bfr[4];
        #pragma unroll
        for (int i = 0; i < 2; i++) af[i]  = *(const bf16x8*)&As[(wm + i * 16 + l16) * 32 + quad * 8];
        #pragma unroll
        for (int j = 0; j < 4; j++) bfr[j] = *(const bf16x8*)&Bs[(j * 16 + l16) * 32 + quad * 8];
        #pragma unroll
        for (int i = 0; i < 2; i++)
            #pragma unroll
            for (int j = 0; j < 4; j++)
                acc[i][j] = MFMA16(af[i], bfr[j], acc[i][j], 0, 0, 0);
    }

    #pragma unroll
    for (int i = 0; i < 2; i++)
        #pragma unroll
        for (int j = 0; j < 4; j++)
            #pragma unroll
            for (int r = 0; r < 4; r++) {
                int mr = bm + wm + i * 16 + quad * 4 + r;
                int nc = bn + j * 16 + l16;
                C[(size_t)mr * 1024 + nc] = acc[i][j][r];
            }
}

// ---------- Flash attention: unpaired, K LDS-dbuf (stride-32 halves), V direct ----------
// grid 1024: cx=bid&7 (XCD), mm=bid>>3, bh=(mm&3)*8+cx, qt=31-(mm>>2) (longest
// first). Wave w owns 16 queries. K staged as lo/hi 64x32 halves (2-way banks =
// free). V register loads issued BEFORE next-tile DMA so the PV waitcnt retires
// V at vmcnt(2), leaving the K prefetch in flight. Fixed-max softmax; q
// pre-scaled by CSC in rope. 25.6 KB LDS, lean VGPR -> 4 blocks/CU.
__global__ __launch_bounds__(256, 4) void attn_kernel(const u16* __restrict__ Q,
                                                      const u16* __restrict__ Kb,
                                                      const u16* __restrict__ Vt,
                                                      u16* __restrict__ Oout) {
    __shared__ __align__(16) u16 KS[2][4096];    // per buf: Klo(64x32) | Khi(64x32)
    __shared__ __align__(16) u16 PW[4][16 * 72]; // per-wave P: 16 rows x 72 u16
    const int tid  = threadIdx.x;
    const int wave = tid >> 6, lane = tid & 63;
    const int l16  = lane & 15, quad = lane >> 4;
    const int bid  = blockIdx.x;
    const int cx   = bid & 7;
    const int mm   = bid >> 3;
    const int bh   = (mm & 3) * 8 + cx;
    const int qt   = 31 - (mm >> 2);
    const int T    = qt + 1;                     // 64-key tiles
    const int q0   = qt * 64 + wave * 16;

    const u16* Qh = Q  + (size_t)bh * 2048 * 64;
    const u16* Kh = Kb + (size_t)bh * 2048 * 64;
    const u16* Vh = Vt + (size_t)bh * 64 * 2048;

    bf16x8 qf0 = *(const bf16x8*)&Qh[(size_t)(q0 + l16) * 64 + quad * 8];
    bf16x8 qf1 = *(const bf16x8*)&Qh[(size_t)(q0 + l16) * 64 + 32 + quad * 8];

    f32x4 o[4];
    float ls[4];
    #pragma unroll
    for (int dn = 0; dn < 4; dn++)
        #pragma unroll
        for (int e = 0; e < 4; e++) o[dn][e] = 0.0f;
    #pragma unroll
    for (int r = 0; r < 4; r++) ls[r] = 0.0f;

    // staging: thread tid loads 16B: key = tid>>2, dims (tid&3)*8 (+32 for hi)
    const u16* gK = Kh + (size_t)(tid >> 2) * 64 + (tid & 3) * 8;
    u16* pw16 = PW[wave];
    u32* pw32 = (u32*)pw16;

    auto stage = [&](int t, int buf) {
        gl_lds16(gK + (size_t)t * 4096,      &KS[buf][(size_t)tid * 8]);
        gl_lds16(gK + (size_t)t * 4096 + 32, &KS[buf][2048 + (size_t)tid * 8]);
    };

    stage(0, 0);
    for (int t = 0; t < T; ++t) {
        __syncthreads();                  // drains vmcnt: buf[t&1] ready
        const int kbase = t * 64;

        // V frags first (older in vmcnt order than the prefetch DMA below)
        bf16x8 vf0[4], vf1[4];
        #pragma unroll
        for (int n = 0; n < 4; n++) {
            const u16* vp = &Vh[(size_t)(n * 16 + l16) * 2048 + kbase + quad * 8];
            vf0[n] = *(const bf16x8*)vp;
            vf1[n] = *(const bf16x8*)(vp + 32);
        }
        asm volatile("" ::: "memory");    // keep DMA issue after the V loads
        if (t + 1 < T) stage(t + 1, (t + 1) & 1);

        const u16* B = KS[t & 1];
        f32x4 s[4];
        #pragma unroll
        for (int n = 0; n < 4; n++) {
            int ri = (n * 16 + l16) * 32 + quad * 8;
            bf16x8 kf0 = *(const bf16x8*)&B[ri];
            bf16x8 kf1 = *(const bf16x8*)&B[2048 + ri];
            #pragma unroll
            for (int e = 0; e < 4; e++) s[n][e] = 0.0f;
            s[n] = MFMA16(qf0, kf0, s[n], 0, 0, 0);
            s[n] = MFMA16(qf1, kf1, s[n], 0, 0, 0);
        }

        const bool diag = (t == T - 1);
        float p[4][4];
        #pragma unroll
        for (int n = 0; n < 4; n++)
            #pragma unroll
            for (int r = 0; r < 4; r++) {
                float v = exp2_fast(s[n][r]);    // q pre-scaled by CSC
                if (diag) {
                    int row = q0 + quad * 4 + r;
                    v = (kbase + n * 16 + l16 > row) ? 0.0f : v;
                }
                p[n][r] = v;
                ls[r] += v;
            }
        // stored u32 col cc*16+l16 <-> real keys (2cc*16+l16, (2cc+1)*16+l16)
        // == per-32 ileave, matching vtb's stored-key permutation
        #pragma unroll
        for (int cc = 0; cc < 2; cc++)
            #pragma unroll
            for (int r = 0; r < 4; r++)
                pw32[(quad * 4 + r) * 36 + cc * 16 + l16] =
                    pack2bf(p[2 * cc][r], p[2 * cc + 1][r]);
        asm volatile("s_waitcnt lgkmcnt(0)" ::: "memory");   // wave-local drain
        bf16x8 pf0 = *(const bf16x8*)&pw16[l16 * 72 + quad * 8];
        bf16x8 pf1 = *(const bf16x8*)&pw16[l16 * 72 + 32 + quad * 8];
        #pragma unroll
        for (int dn = 0; dn < 4; dn++) {
            o[dn] = MFMA16(pf0, vf0[dn], o[dn], 0, 0, 0);
            o[dn] = MFMA16(pf1, vf1[dn], o[dn], 0, 0, 0);
        }
    }

    #pragma unroll
    for (int off = 1; off < 16; off <<= 1)
        #pragma unroll
        for (int r = 0; r < 4; r++) ls[r] += __shfl_xor(ls[r], off);

    const int b = bh >> 4, h = bh & 15;
    #pragma unroll
    for (int r = 0; r < 4; r++) {
        float inv = 1.0f / ls[r];
        int srow = q0 + quad * 4 + r;
        #pragma unroll
        for (int dn = 0; dn < 4; dn++) {
            int d = h * 64 + dn * 16 + l16;
            Oout[((size_t)b * 2048 + srow) * 1024 + d] = f2bf(o[dn][r] * inv);
        }
    }
}

extern "C" void kernel_launch(void* const* d_in, const int* in_sizes, int n_in,
                              void* d_out, int out_size, void* d_ws, size_t ws_size,
                              hipStream_t stream) {
    const float* x  = (const float*)d_in[0];
    const float* wq = (const float*)d_in[1];
    const float* wk = (const float*)d_in[2];
    const float* wv = (const float*)d_in[3];
    const float* wo = (const float*)d_in[4];
    float* out = (float*)d_out;

    const int M = 4096, D = 1024;
    u16* xb    = (u16*)d_ws;                      // [4096,1024]            8 MB
    u16* qkvw  = xb   + (size_t)M * D;            // wq|wk|wv bf16          6 MB
    u16* ow    = qkvw + (size_t)3 * D * D;        // wo bf16                2 MB
    u16* qkv   = ow   + (size_t)D * D;            // q | k | v^T            24 MB
    u16* qb    = qkv;
    u16* kb    = qkv + (size_t)M * D;
    u16* vtb   = qkv + (size_t)2 * M * D;
    u16* aob   = qkv + (size_t)3 * M * D;         // attn out bf16 [B,S,D]  8 MB

    cvt_all_kernel<<<8192, 256, 0, stream>>>(x, wq, wk, wv, wo, xb, qkvw, ow);

    dim3 gq(32, 24);                               // 768 blocks = 3/CU
    gemm_qkv<<<gq, 256, 0, stream>>>(xb, qkvw, qkv, D);

    dim3 gr(2048, 2);                              // b128 rope; q pre-scaled by CSC
    rope_kernel<<<gr, 256, 0, stream>>>(qb, kb);

    attn_kernel<<<1024, 256, 0, stream>>>(qb, kb, vtb, aob);

    dim3 go(32, 16);                               // 512 blocks, 128x64 tiles
    gemm_out<<<go, 256, 0, stream>>>(aob, ow, out, D);
}